// Round 11
// baseline (161.975 us; speedup 1.0000x reference)
//
#include <hip/hip_runtime.h>
#include <hip/hip_bf16.h>
#include <math.h>

#define N_NODES 100000
#define E_EDGES 1000000
#define HEADS 4
#define DIM 64
#define NEG_SLOPE 0.2f
#define SM_EPS 1e-16f
#define LN_EPS 1e-5f
#define P1_BLOCKS 256            // binning chunks
#define NT16 6250                // 100000 / 16 node-tiles, exact
#define GEMM_BLOCKS 782          // ceil(6250 / 8 waves)
#define K1_BLOCKS (P1_BLOCKS + GEMM_BLOCKS)
#define CHUNK 3907               // edges per binning block; 256*3907 >= E
#define EPT 8                    // edges per thread (8*512 = 4096 >= CHUNK)
#define BUCKET_W 512             // nodes per bucket
#define NBUCK 196                // ceil(N / BUCKET_W)
#define MAXE2 8                  // bin2 reg-cache: 8*1024 = 8192 >> ~5200 avg

typedef __attribute__((ext_vector_type(8))) short short8v;  // 8 bf16 = 4 VGPR
typedef __attribute__((ext_vector_type(4))) float f32x4;

static __device__ __forceinline__ unsigned short bfh(float f) {
    __hip_bfloat16 b = __float2bfloat16(f);
    return *reinterpret_cast<unsigned short*>(&b);
}
static __device__ __forceinline__ float bfh2f(unsigned short u) {
    return __uint_as_float((unsigned)u << 16);
}

// K1: fused role-split kernel (R18, verified: 156->148.8).
//  blocks [0,256): bucket-sort own 3907-edge chunk in LDS.
//  blocks [256,1038): 8 waves x one 16-node MFMA tile; W -> bf16 hi/lo
//    B-frags staged in LDS by the whole block first.
__global__ __launch_bounds__(512) void k_feat(
        const float* __restrict__ x, const float* __restrict__ W,
        const float* __restrict__ att_src, const float* __restrict__ att_dst,
        const int* __restrict__ ei, __hip_bfloat16* __restrict__ hb,
        float* __restrict__ asrc, float* __restrict__ adst,
        int2* __restrict__ chunkbuf, int* __restrict__ pre) {
    // bin: out2[3907]int2 + cnt[256] + scan[256] = 33.3 KB; gemm: Wf 16 KB
    __shared__ __align__(16) int smem_i[8326];
    int t = threadIdx.x;

    if (blockIdx.x < P1_BLOCKS) {
        int2* out2 = (int2*)smem_i;             // [CHUNK]
        int*  cnt  = smem_i + 2 * CHUNK;        // [256] counts, later cursors
        int*  scan = cnt + 256;                 // [256]
        int base_e = blockIdx.x * CHUNK;
        int es[EPT], ed[EPT];
#pragma unroll
        for (int k = 0; k < EPT; ++k) {
            int i = k * 512 + t;
            int e = base_e + i;
            bool v = (i < CHUNK) && (e < E_EDGES);
            es[k] = v ? ei[e] : 0;
            ed[k] = v ? ei[E_EDGES + e] : -1;   // -1 = invalid sentinel
        }
        if (t < 256) cnt[t] = 0;
        __syncthreads();
#pragma unroll
        for (int k = 0; k < EPT; ++k)
            if (ed[k] >= 0) atomicAdd(&cnt[ed[k] >> 9], 1);
        __syncthreads();
        if (t < 256) scan[t] = (t < NBUCK) ? cnt[t] : 0;
        __syncthreads();
#pragma unroll
        for (int off = 1; off < 256; off <<= 1) {   // Hillis-Steele inclusive
            int v = (t >= off && t < 256) ? scan[t - off] : 0;
            __syncthreads();
            if (t < 256) scan[t] += v;
            __syncthreads();
        }
        if (t < 256) {
            int excl = (t == 0) ? 0 : scan[t - 1];
            if (t < NBUCK) pre[blockIdx.x * (NBUCK + 1) + t] = excl;
            if (t == 0)    pre[blockIdx.x * (NBUCK + 1) + NBUCK] = scan[NBUCK - 1];
            if (t < NBUCK) cnt[t] = excl;       // reuse cnt as scatter cursor
        }
        __syncthreads();
#pragma unroll
        for (int k = 0; k < EPT; ++k)
            if (ed[k] >= 0) {
                int pos = atomicAdd(&cnt[ed[k] >> 9], 1);
                out2[pos] = make_int2(es[k], ed[k]);
            }
        __syncthreads();
        int ec = E_EDGES - base_e; ec = (ec > CHUNK) ? CHUNK : ec;
        for (int i = t; i < ec; i += 512)       // coalesced dump
            chunkbuf[base_e + i] = out2[i];
        return;
    }

    // ---- GEMM path ----
    uint4* Wlds = (uint4*)smem_i;               // [1024] = 16 KB
    for (int e = t; e < 1024; e += 512) {
        int l = e & 63, f = e >> 6;
        int s = f & 1, kh = (f >> 1) & 1, n = f >> 2;
        int c = n * 16 + (l & 15);
        int k0 = kh * 32 + (l >> 4) * 8;
        unsigned short hw[8];
#pragma unroll
        for (int j = 0; j < 8; ++j) {
            float wv = W[(k0 + j) * 64 + c];    // L2-hot after first block
            unsigned short hi = bfh(wv);
            hw[j] = s ? bfh(wv - bfh2f(hi)) : hi;
        }
        uint4 pk;
        pk.x = hw[0] | ((unsigned)hw[1] << 16);
        pk.y = hw[2] | ((unsigned)hw[3] << 16);
        pk.z = hw[4] | ((unsigned)hw[5] << 16);
        pk.w = hw[6] | ((unsigned)hw[7] << 16);
        Wlds[e] = pk;
    }
    __syncthreads();                            // all 8 waves participate

    int w = t >> 6, lane = t & 63;
    int tile = (blockIdx.x - P1_BLOCKS) * 8 + w;
    if (tile >= NT16) return;                   // after barrier: safe
    int base = tile * 16;
    int m = lane & 15, kg = lane >> 4;          // A row sel / k-group

    const float* xr = x + (size_t)(base + m) * 64 + kg * 8;
    short8v ah[2], al[2];
#pragma unroll
    for (int kh = 0; kh < 2; ++kh) {
        float4 q0 = *(const float4*)(xr + kh * 32);
        float4 q1 = *(const float4*)(xr + kh * 32 + 4);
        float qq[8] = {q0.x, q0.y, q0.z, q0.w, q1.x, q1.y, q1.z, q1.w};
#pragma unroll
        for (int j = 0; j < 8; ++j) {
            unsigned short h = bfh(qq[j]);
            ah[kh][j] = (short)h;
            al[kh][j] = (short)bfh(qq[j] - bfh2f(h));
        }
    }

    const short8v* Wfv = (const short8v*)Wlds;
    float vs_keep = 0.f, vd_keep = 0.f;
#pragma unroll
    for (int n = 0; n < 4; ++n) {               // coltile n == head n
        short8v bh0 = Wfv[((n * 2 + 0) * 2 + 0) * 64 + lane];
        short8v bl0 = Wfv[((n * 2 + 0) * 2 + 1) * 64 + lane];
        short8v bh1 = Wfv[((n * 2 + 1) * 2 + 0) * 64 + lane];
        short8v bl1 = Wfv[((n * 2 + 1) * 2 + 1) * 64 + lane];
        f32x4 a4 = {0.f, 0.f, 0.f, 0.f};
        a4 = __builtin_amdgcn_mfma_f32_16x16x32_bf16(ah[0], bh0, a4, 0, 0, 0);
        a4 = __builtin_amdgcn_mfma_f32_16x16x32_bf16(al[0], bh0, a4, 0, 0, 0);
        a4 = __builtin_amdgcn_mfma_f32_16x16x32_bf16(ah[0], bl0, a4, 0, 0, 0);
        a4 = __builtin_amdgcn_mfma_f32_16x16x32_bf16(ah[1], bh1, a4, 0, 0, 0);
        a4 = __builtin_amdgcn_mfma_f32_16x16x32_bf16(al[1], bh1, a4, 0, 0, 0);
        a4 = __builtin_amdgcn_mfma_f32_16x16x32_bf16(ah[1], bl1, a4, 0, 0, 0);
        float asv = att_src[n * 16 + m];
        float adv = att_dst[n * 16 + m];
#pragma unroll
        for (int ri = 0; ri < 4; ++ri) {
            int orow = base + kg * 4 + ri;      // C/D: row=(lane>>4)*4+reg
            hb[(size_t)orow * 64 + n * 16 + m] = __float2bfloat16(a4[ri]);
            float p = a4[ri] * asv, pd = a4[ri] * adv;
#pragma unroll
            for (int off = 1; off < 16; off <<= 1) {   // 16-wide butterfly
                p  += __shfl_xor(p,  off, 64);
                pd += __shfl_xor(pd, off, 64);
            }
            if (m == ri * 4 + n) { vs_keep = p; vd_keep = pd; }
        }
    }
    asrc[tile * 64 + kg * 16 + m] = vs_keep;    // 256B/wave coalesced
    adst[tile * 64 + kg * 16 + m] = vd_keep;
}

// K-bin2: compact-CSR placement + R20: per-edge softmax-numerator
// precompute. R10 post-mortem: k_aggr is L2/L3 line-request-bound; its
// asrc gathers (4 random lines/instr) + 4x-redundant exp were ~1/3 of the
// inner loop. Placement time knows both endpoints -> compute
// p[h] = exp(lrelu(asrc[src][h]+adst[dst][h])) here (identical math,
// bit-identical output) and store float4 at the edge's CSR slot. asrc
// gathers are issued from the register-cached edges BEFORE the scan phase
// (latency hides under the two LDS scans); adst window is 8KB, L1-hot.
__global__ __launch_bounds__(1024) void k_bin2(
        const int2* __restrict__ chunkbuf, const int* __restrict__ pre,
        const float* __restrict__ asrc, const float* __restrict__ adst,
        int* __restrict__ cursorP, int* __restrict__ srclist,
        float4* __restrict__ pbuf) {
    __shared__ int cnt2[BUCKET_W];          // counts, then place-cursors
    __shared__ int segstart[P1_BLOCKS];
    __shared__ int segpre[P1_BLOCKS + 1];
    __shared__ int scan[P1_BLOCKS];
    int t = threadIdx.x;
    int b = blockIdx.x;
    int nbase = b * BUCKET_W;
    const float4* asrc4 = (const float4*)asrc;
    const float4* adst4 = (const float4*)adst;
    if (t < BUCKET_W) cnt2[t] = 0;
    int p0 = 0, p1 = 0;
    if (t < 256) {
        p0 = pre[t * (NBUCK + 1) + b];
        p1 = pre[t * (NBUCK + 1) + b + 1];
        segstart[t] = t * CHUNK + p0;
        scan[t] = p0;                           // for gbase reduction
    }
    __syncthreads();
#pragma unroll
    for (int off = 128; off >= 1; off >>= 1) {  // tree reduce sum(p0)
        int v = (t < off) ? scan[t + off] : 0;
        __syncthreads();
        if (t < off) scan[t] += v;
        __syncthreads();
    }
    int gbase = scan[0];                        // bucket's global edge base
    __syncthreads();
    if (t < 256) scan[t] = p1 - p0;
    __syncthreads();
#pragma unroll
    for (int off = 1; off < 256; off <<= 1) {   // Hillis-Steele inclusive
        int v = (t >= off && t < 256) ? scan[t - off] : 0;
        __syncthreads();
        if (t < 256) scan[t] += v;
        __syncthreads();
    }
    if (t < 256) segpre[t + 1] = scan[t];
    if (t == 0) segpre[0] = 0;
    __syncthreads();
    int total = segpre[P1_BLOCKS];
    // pass 1: gather + count (edges register-cached)
    int2 ecache[MAXE2];
#pragma unroll
    for (int ii = 0; ii < MAXE2; ++ii) {
        int i = ii * 1024 + t;
        if (i < total) {
            int lo = 0, hi = P1_BLOCKS;
#pragma unroll
            for (int it = 0; it < 8; ++it) {
                int mid = (lo + hi) >> 1;
                if (segpre[mid] <= i) lo = mid; else hi = mid;
            }
            int2 e = chunkbuf[segstart[lo] + (i - segpre[lo])];
            ecache[ii] = e;
            atomicAdd(&cnt2[e.y - nbase], 1);
        }
    }
    for (int i = MAXE2 * 1024 + t; i < total; i += 1024) {  // safety tail
        int lo = 0, hi = P1_BLOCKS;
#pragma unroll
        for (int it = 0; it < 8; ++it) {
            int mid = (lo + hi) >> 1;
            if (segpre[mid] <= i) lo = mid; else hi = mid;
        }
        int2 e = chunkbuf[segstart[lo] + (i - segpre[lo])];
        atomicAdd(&cnt2[e.y - nbase], 1);
    }
    // issue asrc gathers NOW -- latency hides under the scans below
    float4 a4c[MAXE2];
#pragma unroll
    for (int ii = 0; ii < MAXE2; ++ii) {
        int i = ii * 1024 + t;
        if (i < total) a4c[ii] = asrc4[ecache[ii].x];
    }
    __syncthreads();
    // scan cnt2[512] with 256 threads (pair scheme)
    int c0 = 0, c1 = 0;
    if (t < 256) {
        c0 = cnt2[2 * t]; c1 = cnt2[2 * t + 1];
        scan[t] = c0 + c1;
    }
    __syncthreads();
#pragma unroll
    for (int off = 1; off < 256; off <<= 1) {
        int v = (t >= off && t < 256) ? scan[t - off] : 0;
        __syncthreads();
        if (t < 256) scan[t] += v;
        __syncthreads();
    }
    if (t < 256) {
        int pexcl = (t == 0) ? 0 : scan[t - 1];
        cnt2[2 * t]     = pexcl;                // place cursors (in-bucket)
        cnt2[2 * t + 1] = pexcl + c0;
        int n0 = nbase + 2 * t;
        if (n0 < N_NODES)     cursorP[n0]     = ((gbase + pexcl) << 6) | c0;
        if (n0 + 1 < N_NODES) cursorP[n0 + 1] = ((gbase + pexcl + c0) << 6) | c1;
    }
    __syncthreads();
    // pass 2: place src id + softmax numerator p4 (contiguous window)
#pragma unroll
    for (int ii = 0; ii < MAXE2; ++ii) {
        int i = ii * 1024 + t;
        if (i < total) {
            int2 e = ecache[ii];
            int pos = atomicAdd(&cnt2[e.y - nbase], 1);
            srclist[gbase + pos] = e.x;
            float4 a4 = a4c[ii];
            float4 d4 = adst4[e.y];             // 8KB window, L1-hot
            float4 pv;
            float e0 = a4.x + d4.x; e0 = (e0 >= 0.f) ? e0 : NEG_SLOPE * e0;
            float e1 = a4.y + d4.y; e1 = (e1 >= 0.f) ? e1 : NEG_SLOPE * e1;
            float e2 = a4.z + d4.z; e2 = (e2 >= 0.f) ? e2 : NEG_SLOPE * e2;
            float e3 = a4.w + d4.w; e3 = (e3 >= 0.f) ? e3 : NEG_SLOPE * e3;
            pv.x = __expf(e0); pv.y = __expf(e1);
            pv.z = __expf(e2); pv.w = __expf(e3);
            pbuf[gbase + pos] = pv;
        }
    }
    for (int i = MAXE2 * 1024 + t; i < total; i += 1024) {  // safety tail
        int lo = 0, hi = P1_BLOCKS;
#pragma unroll
        for (int it = 0; it < 8; ++it) {
            int mid = (lo + hi) >> 1;
            if (segpre[mid] <= i) lo = mid; else hi = mid;
        }
        int2 e = chunkbuf[segstart[lo] + (i - segpre[lo])];
        int pos = atomicAdd(&cnt2[e.y - nbase], 1);
        srclist[gbase + pos] = e.x;
        float4 a4 = asrc4[e.x];
        float4 d4 = adst4[e.y];
        float4 pv;
        float e0 = a4.x + d4.x; e0 = (e0 >= 0.f) ? e0 : NEG_SLOPE * e0;
        float e1 = a4.y + d4.y; e1 = (e1 >= 0.f) ? e1 : NEG_SLOPE * e1;
        float e2 = a4.z + d4.z; e2 = (e2 >= 0.f) ? e2 : NEG_SLOPE * e2;
        float e3 = a4.w + d4.w; e3 = (e3 >= 0.f) ? e3 : NEG_SLOPE * e3;
        pv.x = __expf(e0); pv.y = __expf(e1);
        pv.z = __expf(e2); pv.w = __expf(e3);
        pbuf[gbase + pos] = pv;
    }
}

// K2: fused aggregation + bias + LayerNorm, 2 nodes/wave. R20: p read
// contiguously from pbuf (1 line per 4 edges vs 4 random asrc lines);
// no lrelu/exp/add in the loop; only remaining indirection is sl -> hb.
__global__ __launch_bounds__(256) void k_aggr(
        const int* __restrict__ cursorP, const int* __restrict__ srclist,
        const float* __restrict__ pbuf,
        const __hip_bfloat16* __restrict__ hb,
        const float* __restrict__ bias, const float* __restrict__ gamma,
        const float* __restrict__ beta, float* __restrict__ out) {
    int t = threadIdx.x;
    int lane = t & 63;
    int s = lane >> 5, qq = (lane >> 4) & 1, j = lane & 15;
    int hd = j >> 2;
    int node = blockIdx.x * 8 + (t >> 6) * 2 + s;   // N/8 blocks exact
    int cw = cursorP[node];
    int dcnt = cw & 63;
    int pbase = (unsigned)cw >> 6;
    const int* sl = srclist + pbase;
    const float* pb = pbuf + (size_t)pbase * 4 + hd;   // this lane's head
    const ushort4* hp = (const ushort4*)hb;     // 16 ushort4 per node row
    float acc0 = 0.f, acc1 = 0.f, acc2 = 0.f, acc3 = 0.f, l = 0.f;

    // batched slots 0..15 (covers deg<=16; all loads in flight together)
    int idx[8];
    float pv[8];
    ushort4 hv[8];
#pragma unroll
    for (int k = 0; k < 8; ++k) {
        int ek = 2 * k + qq;
        idx[k] = (ek < dcnt) ? sl[ek] : 0;      // value-select: safe hb addr
        pv[k] = pb[ek * 4];                     // contiguous; pad-safe
    }
#pragma unroll
    for (int k = 0; k < 8; ++k) hv[k] = hp[idx[k] * 16 + j];
#pragma unroll
    for (int k = 0; k < 8; ++k) {
        int ek = 2 * k + qq;
        float p = (ek < dcnt) ? pv[k] : 0.f;
        l += p;
        acc0 += p * __uint_as_float((unsigned)hv[k].x << 16);
        acc1 += p * __uint_as_float((unsigned)hv[k].y << 16);
        acc2 += p * __uint_as_float((unsigned)hv[k].z << 16);
        acc3 += p * __uint_as_float((unsigned)hv[k].w << 16);
    }
    // rare tail: deg > 16
    int dmax = max(dcnt, __shfl_xor(dcnt, 32, 64)); // wave-uniform bound
    for (int i0 = 16; i0 < dmax; i0 += 8) {
        int idt[4];
        float pvt[4];
        ushort4 hvt[4];
#pragma unroll
        for (int k = 0; k < 4; ++k) {
            int ek = i0 + 2 * k + qq;
            idt[k] = (ek < dcnt) ? sl[ek] : 0;
            pvt[k] = pb[ek * 4];
        }
#pragma unroll
        for (int k = 0; k < 4; ++k) hvt[k] = hp[idt[k] * 16 + j];
#pragma unroll
        for (int k = 0; k < 4; ++k) {
            int ek = i0 + 2 * k + qq;
            float p = (ek < dcnt) ? pvt[k] : 0.f;
            l += p;
            acc0 += p * __uint_as_float((unsigned)hvt[k].x << 16);
            acc1 += p * __uint_as_float((unsigned)hvt[k].y << 16);
            acc2 += p * __uint_as_float((unsigned)hvt[k].z << 16);
            acc3 += p * __uint_as_float((unsigned)hvt[k].w << 16);
        }
    }
    // merge qq pair (lane^16 has same s, same j)
    acc0 += __shfl_xor(acc0, 16, 64);
    acc1 += __shfl_xor(acc1, 16, 64);
    acc2 += __shfl_xor(acc2, 16, 64);
    acc3 += __shfl_xor(acc3, 16, 64);
    l    += __shfl_xor(l,    16, 64);

    float inv = 1.f / (l + SM_EPS);
    float4 b4 = ((const float4*)bias)[j];
    float v0 = acc0 * inv + b4.x;
    float v1 = acc1 * inv + b4.y;
    float v2 = acc2 * inv + b4.z;
    float v3 = acc3 * inv + b4.w;
    float s1 = (v0 + v1) + (v2 + v3);
    float s2 = (v0 * v0 + v1 * v1) + (v2 * v2 + v3 * v3);
#pragma unroll
    for (int off = 1; off < 16; off <<= 1) {    // width-16: stays in s,qq
        s1 += __shfl_xor(s1, off, 64);
        s2 += __shfl_xor(s2, off, 64);
    }
    float mu = s1 * (1.f / 64.f);
    float var = s2 * (1.f / 64.f) - mu * mu;
    float r = rsqrtf(var + LN_EPS);
    if (qq == 0) {                              // lanes 0-15 & 32-47 store
        float4 g4 = ((const float4*)gamma)[j];
        float4 be4 = ((const float4*)beta)[j];
        float4 o;
        o.x = (v0 - mu) * r * g4.x + be4.x;
        o.y = (v1 - mu) * r * g4.y + be4.y;
        o.z = (v2 - mu) * r * g4.z + be4.z;
        o.w = (v3 - mu) * r * g4.w + be4.w;
        ((float4*)(out + (size_t)node * DIM))[j] = o;
    }
}

extern "C" void kernel_launch(void* const* d_in, const int* in_sizes, int n_in,
                              void* d_out, int out_size, void* d_ws, size_t ws_size,
                              hipStream_t stream) {
    const float* x       = (const float*)d_in[0];
    const int*   ei      = (const int*)d_in[1];   // [2,E] int32 (JAX x64 off)
    const float* W       = (const float*)d_in[2];
    const float* att_src = (const float*)d_in[3];
    const float* att_dst = (const float*)d_in[4];
    const float* bias    = (const float*)d_in[5];
    const float* gamma   = (const float*)d_in[6];
    const float* beta    = (const float*)d_in[7];
    float* out = (float*)d_out;

    // ws: chunkbuf[256*CHUNK]int2 (8.0MB) | pre[256*197]i (0.2MB) |
    //     cursorP[N]i | srclist[E+64]i (4.0MB) | asrc/adst (3.2MB) |
    //     hb (12.8MB) | pbuf[E+64]float4 (16MB) ~= 44.6MB
    int2* chunkbuf = (int2*)d_ws;
    int*  pre      = (int*)(chunkbuf + (size_t)P1_BLOCKS * CHUNK);
    int*  cursorP  = pre + (size_t)P1_BLOCKS * (NBUCK + 1);
    int*  srclist  = cursorP + N_NODES;
    float* asrc    = (float*)(srclist + (size_t)E_EDGES + 64);
    float* adst    = asrc + (size_t)N_NODES * HEADS;
    __hip_bfloat16* hb = (__hip_bfloat16*)(adst + (size_t)N_NODES * HEADS);
    float4* pbuf   = (float4*)(hb + (size_t)N_NODES * DIM);

    k_feat<<<K1_BLOCKS, 512, 0, stream>>>(x, W, att_src, att_dst, ei,
                                          hb, asrc, adst, chunkbuf, pre);
    k_bin2<<<NBUCK, 1024, 0, stream>>>(chunkbuf, pre, asrc, adst,
                                       cursorP, srclist, pbuf);
    k_aggr<<<N_NODES / 8, 256, 0, stream>>>(cursorP, srclist, (const float*)pbuf,
                                            hb, bias, gamma, beta, out);
}

// Round 12
// 144.209 us; speedup vs baseline: 1.1232x; 1.1232x over previous
//
#include <hip/hip_runtime.h>
#include <hip/hip_bf16.h>
#include <math.h>

#define N_NODES 100000
#define E_EDGES 1000000
#define HEADS 4
#define DIM 64
#define NEG_SLOPE 0.2f
#define SM_EPS 1e-16f
#define LN_EPS 1e-5f
#define P1_BLOCKS 256            // binning chunks
#define NT16 6250                // 100000 / 16 node-tiles, exact
#define GEMM_BLOCKS 782          // ceil(6250 / 8 waves)
#define K1_BLOCKS (P1_BLOCKS + GEMM_BLOCKS)
#define CHUNK 3907               // edges per binning block; 256*3907 >= E
#define EPT 8                    // edges per thread (8*512 = 4096 >= CHUNK)
#define BUCKET_W 512             // nodes per bucket
#define NBUCK 196                // ceil(N / BUCKET_W)
#define MAXE2 8                  // bin2 reg-cache: 8*1024 = 8192 >> ~5200 avg

typedef __attribute__((ext_vector_type(8))) short short8v;  // 8 bf16 = 4 VGPR
typedef __attribute__((ext_vector_type(4))) float f32x4;

static __device__ __forceinline__ unsigned short bfh(float f) {
    __hip_bfloat16 b = __float2bfloat16(f);
    return *reinterpret_cast<unsigned short*>(&b);
}
static __device__ __forceinline__ float bfh2f(unsigned short u) {
    return __uint_as_float((unsigned)u << 16);
}

// K1: fused role-split kernel (R18, verified: 156->148.8).
//  blocks [0,256): bucket-sort own 3907-edge chunk in LDS.
//  blocks [256,1038): 8 waves x one 16-node MFMA tile; W -> bf16 hi/lo
//    B-frags staged in LDS by the whole block first.
__global__ __launch_bounds__(512) void k_feat(
        const float* __restrict__ x, const float* __restrict__ W,
        const float* __restrict__ att_src, const float* __restrict__ att_dst,
        const int* __restrict__ ei, __hip_bfloat16* __restrict__ hb,
        float* __restrict__ asrc, float* __restrict__ adst,
        int2* __restrict__ chunkbuf, int* __restrict__ pre) {
    // bin: out2[3907]int2 + cnt[256] + scan[256] = 33.3 KB; gemm: Wf 16 KB
    __shared__ __align__(16) int smem_i[8326];
    int t = threadIdx.x;

    if (blockIdx.x < P1_BLOCKS) {
        int2* out2 = (int2*)smem_i;             // [CHUNK]
        int*  cnt  = smem_i + 2 * CHUNK;        // [256] counts, later cursors
        int*  scan = cnt + 256;                 // [256]
        int base_e = blockIdx.x * CHUNK;
        int es[EPT], ed[EPT];
#pragma unroll
        for (int k = 0; k < EPT; ++k) {
            int i = k * 512 + t;
            int e = base_e + i;
            bool v = (i < CHUNK) && (e < E_EDGES);
            es[k] = v ? ei[e] : 0;
            ed[k] = v ? ei[E_EDGES + e] : -1;   // -1 = invalid sentinel
        }
        if (t < 256) cnt[t] = 0;
        __syncthreads();
#pragma unroll
        for (int k = 0; k < EPT; ++k)
            if (ed[k] >= 0) atomicAdd(&cnt[ed[k] >> 9], 1);
        __syncthreads();
        if (t < 256) scan[t] = (t < NBUCK) ? cnt[t] : 0;
        __syncthreads();
#pragma unroll
        for (int off = 1; off < 256; off <<= 1) {   // Hillis-Steele inclusive
            int v = (t >= off && t < 256) ? scan[t - off] : 0;
            __syncthreads();
            if (t < 256) scan[t] += v;
            __syncthreads();
        }
        if (t < 256) {
            int excl = (t == 0) ? 0 : scan[t - 1];
            if (t < NBUCK) pre[blockIdx.x * (NBUCK + 1) + t] = excl;
            if (t == 0)    pre[blockIdx.x * (NBUCK + 1) + NBUCK] = scan[NBUCK - 1];
            if (t < NBUCK) cnt[t] = excl;       // reuse cnt as scatter cursor
        }
        __syncthreads();
#pragma unroll
        for (int k = 0; k < EPT; ++k)
            if (ed[k] >= 0) {
                int pos = atomicAdd(&cnt[ed[k] >> 9], 1);
                out2[pos] = make_int2(es[k], ed[k]);
            }
        __syncthreads();
        int ec = E_EDGES - base_e; ec = (ec > CHUNK) ? CHUNK : ec;
        for (int i = t; i < ec; i += 512)       // coalesced dump
            chunkbuf[base_e + i] = out2[i];
        return;
    }

    // ---- GEMM path ----
    uint4* Wlds = (uint4*)smem_i;               // [1024] = 16 KB
    for (int e = t; e < 1024; e += 512) {
        int l = e & 63, f = e >> 6;
        int s = f & 1, kh = (f >> 1) & 1, n = f >> 2;
        int c = n * 16 + (l & 15);
        int k0 = kh * 32 + (l >> 4) * 8;
        unsigned short hw[8];
#pragma unroll
        for (int j = 0; j < 8; ++j) {
            float wv = W[(k0 + j) * 64 + c];    // L2-hot after first block
            unsigned short hi = bfh(wv);
            hw[j] = s ? bfh(wv - bfh2f(hi)) : hi;
        }
        uint4 pk;
        pk.x = hw[0] | ((unsigned)hw[1] << 16);
        pk.y = hw[2] | ((unsigned)hw[3] << 16);
        pk.z = hw[4] | ((unsigned)hw[5] << 16);
        pk.w = hw[6] | ((unsigned)hw[7] << 16);
        Wlds[e] = pk;
    }
    __syncthreads();                            // all 8 waves participate

    int w = t >> 6, lane = t & 63;
    int tile = (blockIdx.x - P1_BLOCKS) * 8 + w;
    if (tile >= NT16) return;                   // after barrier: safe
    int base = tile * 16;
    int m = lane & 15, kg = lane >> 4;          // A row sel / k-group

    const float* xr = x + (size_t)(base + m) * 64 + kg * 8;
    short8v ah[2], al[2];
#pragma unroll
    for (int kh = 0; kh < 2; ++kh) {
        float4 q0 = *(const float4*)(xr + kh * 32);
        float4 q1 = *(const float4*)(xr + kh * 32 + 4);
        float qq[8] = {q0.x, q0.y, q0.z, q0.w, q1.x, q1.y, q1.z, q1.w};
#pragma unroll
        for (int j = 0; j < 8; ++j) {
            unsigned short h = bfh(qq[j]);
            ah[kh][j] = (short)h;
            al[kh][j] = (short)bfh(qq[j] - bfh2f(h));
        }
    }

    const short8v* Wfv = (const short8v*)Wlds;
    float vs_keep = 0.f, vd_keep = 0.f;
#pragma unroll
    for (int n = 0; n < 4; ++n) {               // coltile n == head n
        short8v bh0 = Wfv[((n * 2 + 0) * 2 + 0) * 64 + lane];
        short8v bl0 = Wfv[((n * 2 + 0) * 2 + 1) * 64 + lane];
        short8v bh1 = Wfv[((n * 2 + 1) * 2 + 0) * 64 + lane];
        short8v bl1 = Wfv[((n * 2 + 1) * 2 + 1) * 64 + lane];
        f32x4 a4 = {0.f, 0.f, 0.f, 0.f};
        a4 = __builtin_amdgcn_mfma_f32_16x16x32_bf16(ah[0], bh0, a4, 0, 0, 0);
        a4 = __builtin_amdgcn_mfma_f32_16x16x32_bf16(al[0], bh0, a4, 0, 0, 0);
        a4 = __builtin_amdgcn_mfma_f32_16x16x32_bf16(ah[0], bl0, a4, 0, 0, 0);
        a4 = __builtin_amdgcn_mfma_f32_16x16x32_bf16(ah[1], bh1, a4, 0, 0, 0);
        a4 = __builtin_amdgcn_mfma_f32_16x16x32_bf16(al[1], bh1, a4, 0, 0, 0);
        a4 = __builtin_amdgcn_mfma_f32_16x16x32_bf16(ah[1], bl1, a4, 0, 0, 0);
        float asv = att_src[n * 16 + m];
        float adv = att_dst[n * 16 + m];
#pragma unroll
        for (int ri = 0; ri < 4; ++ri) {
            int orow = base + kg * 4 + ri;      // C/D: row=(lane>>4)*4+reg
            hb[(size_t)orow * 64 + n * 16 + m] = __float2bfloat16(a4[ri]);
            float p = a4[ri] * asv, pd = a4[ri] * adv;
#pragma unroll
            for (int off = 1; off < 16; off <<= 1) {   // 16-wide butterfly
                p  += __shfl_xor(p,  off, 64);
                pd += __shfl_xor(pd, off, 64);
            }
            if (m == ri * 4 + n) { vs_keep = p; vd_keep = pd; }
        }
    }
    asrc[tile * 64 + kg * 16 + m] = vs_keep;    // 256B/wave coalesced
    adst[tile * 64 + kg * 16 + m] = vd_keep;
}

// K-bin2: compact-CSR placement (R16/R17 form, R20's pbuf reverted — the
// moved asrc gather wasn't hidden there and pbuf added a 32MB round-trip:
// 148.2 -> 162.0).
__global__ __launch_bounds__(1024) void k_bin2(
        const int2* __restrict__ chunkbuf, const int* __restrict__ pre,
        int* __restrict__ cursorP, int* __restrict__ srclist) {
    __shared__ int cnt2[BUCKET_W];          // counts, then place-cursors
    __shared__ int segstart[P1_BLOCKS];
    __shared__ int segpre[P1_BLOCKS + 1];
    __shared__ int scan[P1_BLOCKS];
    int t = threadIdx.x;
    int b = blockIdx.x;
    int nbase = b * BUCKET_W;
    if (t < BUCKET_W) cnt2[t] = 0;
    int p0 = 0, p1 = 0;
    if (t < 256) {
        p0 = pre[t * (NBUCK + 1) + b];
        p1 = pre[t * (NBUCK + 1) + b + 1];
        segstart[t] = t * CHUNK + p0;
        scan[t] = p0;                           // for gbase reduction
    }
    __syncthreads();
#pragma unroll
    for (int off = 128; off >= 1; off >>= 1) {  // tree reduce sum(p0)
        int v = (t < off) ? scan[t + off] : 0;
        __syncthreads();
        if (t < off) scan[t] += v;
        __syncthreads();
    }
    int gbase = scan[0];                        // bucket's global edge base
    __syncthreads();
    if (t < 256) scan[t] = p1 - p0;
    __syncthreads();
#pragma unroll
    for (int off = 1; off < 256; off <<= 1) {   // Hillis-Steele inclusive
        int v = (t >= off && t < 256) ? scan[t - off] : 0;
        __syncthreads();
        if (t < 256) scan[t] += v;
        __syncthreads();
    }
    if (t < 256) segpre[t + 1] = scan[t];
    if (t == 0) segpre[0] = 0;
    __syncthreads();
    int total = segpre[P1_BLOCKS];
    // pass 1: gather + count (edges register-cached)
    int2 ecache[MAXE2];
#pragma unroll
    for (int ii = 0; ii < MAXE2; ++ii) {
        int i = ii * 1024 + t;
        if (i < total) {
            int lo = 0, hi = P1_BLOCKS;
#pragma unroll
            for (int it = 0; it < 8; ++it) {
                int mid = (lo + hi) >> 1;
                if (segpre[mid] <= i) lo = mid; else hi = mid;
            }
            int2 e = chunkbuf[segstart[lo] + (i - segpre[lo])];
            ecache[ii] = e;
            atomicAdd(&cnt2[e.y - nbase], 1);
        }
    }
    for (int i = MAXE2 * 1024 + t; i < total; i += 1024) {  // safety tail
        int lo = 0, hi = P1_BLOCKS;
#pragma unroll
        for (int it = 0; it < 8; ++it) {
            int mid = (lo + hi) >> 1;
            if (segpre[mid] <= i) lo = mid; else hi = mid;
        }
        int2 e = chunkbuf[segstart[lo] + (i - segpre[lo])];
        atomicAdd(&cnt2[e.y - nbase], 1);
    }
    __syncthreads();
    // scan cnt2[512] with 256 threads (pair scheme)
    int c0 = 0, c1 = 0;
    if (t < 256) {
        c0 = cnt2[2 * t]; c1 = cnt2[2 * t + 1];
        scan[t] = c0 + c1;
    }
    __syncthreads();
#pragma unroll
    for (int off = 1; off < 256; off <<= 1) {
        int v = (t >= off && t < 256) ? scan[t - off] : 0;
        __syncthreads();
        if (t < 256) scan[t] += v;
        __syncthreads();
    }
    if (t < 256) {
        int pexcl = (t == 0) ? 0 : scan[t - 1];
        cnt2[2 * t]     = pexcl;                // place cursors (in-bucket)
        cnt2[2 * t + 1] = pexcl + c0;
        int n0 = nbase + 2 * t;
        if (n0 < N_NODES)     cursorP[n0]     = ((gbase + pexcl) << 6) | c0;
        if (n0 + 1 < N_NODES) cursorP[n0 + 1] = ((gbase + pexcl + c0) << 6) | c1;
    }
    __syncthreads();
    // pass 2: place from register cache (contiguous per-bucket window)
#pragma unroll
    for (int ii = 0; ii < MAXE2; ++ii) {
        int i = ii * 1024 + t;
        if (i < total) {
            int2 e = ecache[ii];
            int pos = atomicAdd(&cnt2[e.y - nbase], 1);
            srclist[gbase + pos] = e.x;
        }
    }
    for (int i = MAXE2 * 1024 + t; i < total; i += 1024) {  // safety tail
        int lo = 0, hi = P1_BLOCKS;
#pragma unroll
        for (int it = 0; it < 8; ++it) {
            int mid = (lo + hi) >> 1;
            if (segpre[mid] <= i) lo = mid; else hi = mid;
        }
        int2 e = chunkbuf[segstart[lo] + (i - segpre[lo])];
        int pos = atomicAdd(&cnt2[e.y - nbase], 1);
        srclist[gbase + pos] = e.x;
    }
}

// K2: fused aggregation + bias + LayerNorm, 2 nodes/wave.
// R21: 8-lanes-per-edge via uint4 (16B/lane) hb loads. R11 post-mortem:
// gather relocation (R20) regressed; attack issue count instead. Per node
// 32 lanes: e4 = (lane>>3)&3 edge-slot group, j8 = lane&7 channel-octet,
// hd = j8>>1. Each lane loads one uint4 = 8 bf16 channels -> per-batch
// load instrs halve (24->12) and per-edge p/exp redundancy halves (2
// lanes/head vs 4). Merge: e4-butterfly (off 8,16), LN j8-reduce
// (off 1,2,4); store 2x float4 per e4==0 lane (256B/node coalesced).
__global__ __launch_bounds__(256) void k_aggr(
        const int* __restrict__ cursorP, const int* __restrict__ srclist,
        const float* __restrict__ asrc, const float* __restrict__ adst,
        const __hip_bfloat16* __restrict__ hb,
        const float* __restrict__ bias, const float* __restrict__ gamma,
        const float* __restrict__ beta, float* __restrict__ out) {
    int t = threadIdx.x;
    int lane = t & 63;
    int s = lane >> 5, e4 = (lane >> 3) & 3, j8 = lane & 7;
    int hd = j8 >> 1;
    int node = blockIdx.x * 8 + (t >> 6) * 2 + s;   // N/8 blocks exact
    int cw = cursorP[node];
    int dcnt = cw & 63;
    const int* sl = srclist + ((unsigned)cw >> 6);
    const uint4* hp = (const uint4*)hb;         // 8 uint4 per node row
    float ad = adst[node * HEADS + hd];
    float a0 = 0.f, a1 = 0.f, a2 = 0.f, a3 = 0.f;
    float a4_ = 0.f, a5 = 0.f, a6 = 0.f, a7 = 0.f, l = 0.f;

    // batch: slots ek = 4k + e4, k=0..3 -> covers 16 slots (deg<=16: 97%)
    int idx[4];
    float as[4];
    uint4 hv[4];
#pragma unroll
    for (int k = 0; k < 4; ++k) {
        int ek = 4 * k + e4;
        idx[k] = (ek < dcnt) ? sl[ek] : 0;      // value-select: safe hb addr
    }
#pragma unroll
    for (int k = 0; k < 4; ++k) as[k] = asrc[idx[k] * HEADS + hd];
#pragma unroll
    for (int k = 0; k < 4; ++k) hv[k] = hp[idx[k] * 8 + j8];
#pragma unroll
    for (int k = 0; k < 4; ++k) {
        int ek = 4 * k + e4;
        float e = as[k] + ad;
        e = (e >= 0.f) ? e : NEG_SLOPE * e;
        float p = (ek < dcnt) ? __expf(e) : 0.f;
        l += p;
        a0 += p * __uint_as_float(hv[k].x << 16);
        a1 += p * __uint_as_float(hv[k].x & 0xffff0000u);
        a2 += p * __uint_as_float(hv[k].y << 16);
        a3 += p * __uint_as_float(hv[k].y & 0xffff0000u);
        a4_ += p * __uint_as_float(hv[k].z << 16);
        a5 += p * __uint_as_float(hv[k].z & 0xffff0000u);
        a6 += p * __uint_as_float(hv[k].w << 16);
        a7 += p * __uint_as_float(hv[k].w & 0xffff0000u);
    }
    // rare tail: deg > 16
    int dmax = max(dcnt, __shfl_xor(dcnt, 32, 64)); // wave-uniform bound
    for (int i0 = 16; i0 < dmax; i0 += 16) {
        int idt[4];
        float ast[4];
        uint4 hvt[4];
#pragma unroll
        for (int k = 0; k < 4; ++k) {
            int ek = i0 + 4 * k + e4;
            idt[k] = (ek < dcnt) ? sl[ek] : 0;
        }
#pragma unroll
        for (int k = 0; k < 4; ++k) ast[k] = asrc[idt[k] * HEADS + hd];
#pragma unroll
        for (int k = 0; k < 4; ++k) hvt[k] = hp[idt[k] * 8 + j8];
#pragma unroll
        for (int k = 0; k < 4; ++k) {
            int ek = i0 + 4 * k + e4;
            float e = ast[k] + ad;
            e = (e >= 0.f) ? e : NEG_SLOPE * e;
            float p = (ek < dcnt) ? __expf(e) : 0.f;
            l += p;
            a0 += p * __uint_as_float(hvt[k].x << 16);
            a1 += p * __uint_as_float(hvt[k].x & 0xffff0000u);
            a2 += p * __uint_as_float(hvt[k].y << 16);
            a3 += p * __uint_as_float(hvt[k].y & 0xffff0000u);
            a4_ += p * __uint_as_float(hvt[k].z << 16);
            a5 += p * __uint_as_float(hvt[k].z & 0xffff0000u);
            a6 += p * __uint_as_float(hvt[k].w << 16);
            a7 += p * __uint_as_float(hvt[k].w & 0xffff0000u);
        }
    }
    // merge across e4 groups (lane bits 3,4): butterfly -> all lanes full
#pragma unroll
    for (int off = 8; off <= 16; off <<= 1) {
        a0 += __shfl_xor(a0, off, 64);  a1 += __shfl_xor(a1, off, 64);
        a2 += __shfl_xor(a2, off, 64);  a3 += __shfl_xor(a3, off, 64);
        a4_ += __shfl_xor(a4_, off, 64); a5 += __shfl_xor(a5, off, 64);
        a6 += __shfl_xor(a6, off, 64);  a7 += __shfl_xor(a7, off, 64);
        l  += __shfl_xor(l,  off, 64);
    }

    float inv = 1.f / (l + SM_EPS);
    float4 b40 = ((const float4*)bias)[j8 * 2];
    float4 b41 = ((const float4*)bias)[j8 * 2 + 1];
    float v0 = a0 * inv + b40.x, v1 = a1 * inv + b40.y;
    float v2 = a2 * inv + b40.z, v3 = a3 * inv + b40.w;
    float v4 = a4_ * inv + b41.x, v5 = a5 * inv + b41.y;
    float v6 = a6 * inv + b41.z, v7 = a7 * inv + b41.w;
    float s1 = ((v0 + v1) + (v2 + v3)) + ((v4 + v5) + (v6 + v7));
    float s2 = ((v0 * v0 + v1 * v1) + (v2 * v2 + v3 * v3))
             + ((v4 * v4 + v5 * v5) + (v6 * v6 + v7 * v7));
#pragma unroll
    for (int off = 1; off < 8; off <<= 1) {     // j8 bits 0-2: 64 channels
        s1 += __shfl_xor(s1, off, 64);
        s2 += __shfl_xor(s2, off, 64);
    }
    float mu = s1 * (1.f / 64.f);
    float var = s2 * (1.f / 64.f) - mu * mu;
    float r = rsqrtf(var + LN_EPS);
    if (e4 == 0) {                              // 8 lanes/node store 32B each
        float4 g40 = ((const float4*)gamma)[j8 * 2];
        float4 g41 = ((const float4*)gamma)[j8 * 2 + 1];
        float4 be0 = ((const float4*)beta)[j8 * 2];
        float4 be1 = ((const float4*)beta)[j8 * 2 + 1];
        float4 o0, o1;
        o0.x = (v0 - mu) * r * g40.x + be0.x;
        o0.y = (v1 - mu) * r * g40.y + be0.y;
        o0.z = (v2 - mu) * r * g40.z + be0.z;
        o0.w = (v3 - mu) * r * g40.w + be0.w;
        o1.x = (v4 - mu) * r * g41.x + be1.x;
        o1.y = (v5 - mu) * r * g41.y + be1.y;
        o1.z = (v6 - mu) * r * g41.z + be1.z;
        o1.w = (v7 - mu) * r * g41.w + be1.w;
        float4* op = (float4*)(out + (size_t)node * DIM);
        op[j8 * 2]     = o0;                    // 256B/node coalesced
        op[j8 * 2 + 1] = o1;
    }
}

extern "C" void kernel_launch(void* const* d_in, const int* in_sizes, int n_in,
                              void* d_out, int out_size, void* d_ws, size_t ws_size,
                              hipStream_t stream) {
    const float* x       = (const float*)d_in[0];
    const int*   ei      = (const int*)d_in[1];   // [2,E] int32 (JAX x64 off)
    const float* W       = (const float*)d_in[2];
    const float* att_src = (const float*)d_in[3];
    const float* att_dst = (const float*)d_in[4];
    const float* bias    = (const float*)d_in[5];
    const float* gamma   = (const float*)d_in[6];
    const float* beta    = (const float*)d_in[7];
    float* out = (float*)d_out;

    // ws: chunkbuf[256*CHUNK]int2 (8.0MB) | pre[256*197]i (0.2MB) |
    //     cursorP[N]i | srclist[E+64]i (4.0MB) | asrc/adst (3.2MB) |
    //     hb (12.8MB) ~= 28.6MB
    int2* chunkbuf = (int2*)d_ws;
    int*  pre      = (int*)(chunkbuf + (size_t)P1_BLOCKS * CHUNK);
    int*  cursorP  = pre + (size_t)P1_BLOCKS * (NBUCK + 1);
    int*  srclist  = cursorP + N_NODES;
    float* asrc    = (float*)(srclist + (size_t)E_EDGES + 64);
    float* adst    = asrc + (size_t)N_NODES * HEADS;
    __hip_bfloat16* hb = (__hip_bfloat16*)(adst + (size_t)N_NODES * HEADS);

    k_feat<<<K1_BLOCKS, 512, 0, stream>>>(x, W, att_src, att_dst, ei,
                                          hb, asrc, adst, chunkbuf, pre);
    k_bin2<<<NBUCK, 1024, 0, stream>>>(chunkbuf, pre, cursorP, srclist);
    k_aggr<<<N_NODES / 8, 256, 0, stream>>>(cursorP, srclist, asrc, adst, hb,
                                            bias, gamma, beta, out);
}